// Round 2
// baseline (248.968 us; speedup 1.0000x reference)
//
#include <hip/hip_runtime.h>

// MultiScaleRoIAlign: B=2, Nb=256 (R=512 rois), C=256, PH=PW=7, GRID=2.
// R1: no-LDS design. Each thread owns one bin (descriptors in registers),
// loops over channels 2-at-a-time. Grid = R x NCHUNK for occupancy.

#define PHW 49          // 7*7 bins
#define NCHUNK 8
#define CH 32           // 256 / NCHUNK channels per block
#define CSLOTS 5        // channel slots per block (49*5 = 245 active threads)

__global__ __launch_bounds__(256) void msroi_kernel(
    const float* __restrict__ f0, const float* __restrict__ f1,
    const float* __restrict__ f2, const float* __restrict__ f3,
    const float* __restrict__ boxes, float* __restrict__ out)
{
    const int C = 256, Nb = 256;
    const int r = blockIdx.x;            // roi index, 0..511
    const int chunk = blockIdx.y;        // channel chunk, 0..7
    const int tid = threadIdx.x;
    const int c0 = tid / PHW;            // channel slot 0..4 (>=5 idle)
    const int bin = tid - c0 * PHW;      // 0..48
    if (c0 >= CSLOTS) return;            // no barriers below — safe

    const int b = r / Nb;

    // ---- per-roi params (uniform across block) ----
    const float x1b = boxes[r * 4 + 0];
    const float y1b = boxes[r * 4 + 1];
    const float x2b = boxes[r * 4 + 2];
    const float y2b = boxes[r * 4 + 3];
    const float area = fmaxf((x2b - x1b) * (y2b - y1b), 0.0f);
    const float s = sqrtf(area);
    float lv = floorf(4.0f + log2f(s / 224.0f + 1e-6f));
    lv = fminf(fmaxf(lv, 2.0f), 5.0f);
    const int lvl = (int)lv - 2;         // 0..3

    const float* feat;
    int H, W;
    float scale;
    switch (lvl) {
        case 0:  feat = f0; H = 200; W = 200; scale = 0.25f;    break;
        case 1:  feat = f1; H = 100; W = 100; scale = 0.125f;   break;
        case 2:  feat = f2; H = 50;  W = 50;  scale = 0.0625f;  break;
        default: feat = f3; H = 25;  W = 25;  scale = 0.03125f; break;
    }
    const int HW = H * W;

    const float x1 = x1b * scale, y1 = y1b * scale;
    const float x2 = x2b * scale, y2 = y2b * scale;
    const float roi_w = fmaxf(x2 - x1, 1.0f);
    const float roi_h = fmaxf(y2 - y1, 1.0f);
    const float bin_w = roi_w * (1.0f / 7.0f);
    const float bin_h = roi_h * (1.0f / 7.0f);

    // ---- per-bin sample descriptors -> registers (computed once) ----
    const int ph = bin / 7;
    const int pw = bin - ph * 7;
    int   o[16];
    float w[16];
#pragma unroll
    for (int g = 0; g < 4; ++g) {
        const int iy = g >> 1, ix = g & 1;
        const float gy = (float)ph + ((float)iy + 0.5f) * 0.5f;
        const float gx = (float)pw + ((float)ix + 0.5f) * 0.5f;
        const float y = y1 + gy * bin_h;
        const float x = x1 + gx * bin_w;
        const bool valid = (y >= -1.0f) && (y <= (float)H) &&
                           (x >= -1.0f) && (x <= (float)W);
        const float yc = fminf(fmaxf(y, 0.0f), (float)(H - 1));
        const float xc = fminf(fmaxf(x, 0.0f), (float)(W - 1));
        const int yl = (int)floorf(yc);
        const int xl = (int)floorf(xc);
        const int yh = min(yl + 1, H - 1);
        const int xh = min(xl + 1, W - 1);
        const float ly = yc - (float)yl;
        const float lx = xc - (float)xl;
        const float hy = 1.0f - ly, hx = 1.0f - lx;
        const float m = valid ? 0.25f : 0.0f;
        o[g * 4 + 0] = yl * W + xl;  w[g * 4 + 0] = hy * hx * m;
        o[g * 4 + 1] = yl * W + xh;  w[g * 4 + 1] = hy * lx * m;
        o[g * 4 + 2] = yh * W + xl;  w[g * 4 + 2] = ly * hx * m;
        o[g * 4 + 3] = yh * W + xh;  w[g * 4 + 3] = ly * lx * m;
    }

    // ---- channel loop: 2 channels per iteration for MLP ----
    const int cbase = chunk * CH;
    const float* __restrict__ fbase = feat + (size_t)(b * C + cbase) * HW;
    const size_t outBase = (size_t)r * C * PHW + (size_t)cbase * PHW + bin;

    int c = c0;
    for (; c + CSLOTS < CH; c += 2 * CSLOTS) {
        const float* __restrict__ fpA = fbase + (size_t)c * HW;
        const float* __restrict__ fpB = fpA + (size_t)CSLOTS * HW;
        float a0 = 0.0f, a1 = 0.0f;
#pragma unroll
        for (int k = 0; k < 16; ++k) {
            a0 += w[k] * fpA[o[k]];
            a1 += w[k] * fpB[o[k]];
        }
        out[outBase + (size_t)c * PHW] = a0;
        out[outBase + (size_t)(c + CSLOTS) * PHW] = a1;
    }
    if (c < CH) {
        const float* __restrict__ fpA = fbase + (size_t)c * HW;
        float a0 = 0.0f;
#pragma unroll
        for (int k = 0; k < 16; ++k) {
            a0 += w[k] * fpA[o[k]];
        }
        out[outBase + (size_t)c * PHW] = a0;
    }
}

extern "C" void kernel_launch(void* const* d_in, const int* in_sizes, int n_in,
                              void* d_out, int out_size, void* d_ws, size_t ws_size,
                              hipStream_t stream) {
    const float* f0 = (const float*)d_in[0];
    const float* f1 = (const float*)d_in[1];
    const float* f2 = (const float*)d_in[2];
    const float* f3 = (const float*)d_in[3];
    const float* boxes = (const float*)d_in[4];
    float* out = (float*)d_out;

    const int R = in_sizes[4] / 4;   // 512 rois
    dim3 grid(R, NCHUNK);
    msroi_kernel<<<grid, 256, 0, stream>>>(f0, f1, f2, f3, boxes, out);
}

// Round 3
// 238.169 us; speedup vs baseline: 1.0453x; 1.0453x over previous
//
#include <hip/hip_runtime.h>

// MultiScaleRoIAlign: B=2, Nb=256 (R=512 rois), C=256, PH=PW=7, GRID=2.
// R2: LDS patch staging. Per (roi, 32-ch chunk) block: load the roi's
// bounding patch for NC=4 channels at a time into LDS with coalesced
// row-major reads, then evaluate 49 bins/channel from LDS.
// Worst-case patch <= ~980 floats (level-0, 392x32 box) -> PSIZE=1024 safe.

#define PHW 49
#define NCHUNK 8
#define CH 32            // channels per block
#define NC 4             // channels staged per iteration
#define PSIZE 1024       // floats per channel patch (worst case ~980)

__global__ __launch_bounds__(256) void msroi_kernel(
    const float* __restrict__ f0, const float* __restrict__ f1,
    const float* __restrict__ f2, const float* __restrict__ f3,
    const float* __restrict__ boxes, float* __restrict__ out)
{
    const int C = 256, Nb = 256;
    const int r = blockIdx.x;            // roi 0..511
    const int chunk = blockIdx.y;        // 0..7
    const int tid = threadIdx.x;
    const int b = r / Nb;

    // ---- per-roi params (uniform) ----
    const float x1b = boxes[r * 4 + 0];
    const float y1b = boxes[r * 4 + 1];
    const float x2b = boxes[r * 4 + 2];
    const float y2b = boxes[r * 4 + 3];
    const float area = fmaxf((x2b - x1b) * (y2b - y1b), 0.0f);
    const float s = sqrtf(area);
    float lv = floorf(4.0f + log2f(s / 224.0f + 1e-6f));
    lv = fminf(fmaxf(lv, 2.0f), 5.0f);
    const int lvl = (int)lv - 2;

    const float* feat;
    int H, W;
    float scale;
    switch (lvl) {
        case 0:  feat = f0; H = 200; W = 200; scale = 0.25f;    break;
        case 1:  feat = f1; H = 100; W = 100; scale = 0.125f;   break;
        case 2:  feat = f2; H = 50;  W = 50;  scale = 0.0625f;  break;
        default: feat = f3; H = 25;  W = 25;  scale = 0.03125f; break;
    }
    const int HW = H * W;

    const float x1 = x1b * scale, y1 = y1b * scale;
    const float x2 = x2b * scale, y2 = y2b * scale;
    const float roi_w = fmaxf(x2 - x1, 1.0f);
    const float roi_h = fmaxf(y2 - y1, 1.0f);
    const float bin_w = roi_w * (1.0f / 7.0f);
    const float bin_h = roi_h * (1.0f / 7.0f);

    // ---- patch bounds (uniform): samples at gy,gx in {0.25 .. 6.75} ----
    const float ys0 = fminf(fmaxf(y1 + 0.25f * bin_h, 0.0f), (float)(H - 1));
    const float ys1 = fminf(fmaxf(y1 + 6.75f * bin_h, 0.0f), (float)(H - 1));
    const float xs0 = fminf(fmaxf(x1 + 0.25f * bin_w, 0.0f), (float)(W - 1));
    const float xs1 = fminf(fmaxf(x1 + 6.75f * bin_w, 0.0f), (float)(W - 1));
    const int row0 = (int)floorf(ys0);
    const int row1 = min((int)floorf(ys1) + 1, H - 1);
    const int col0 = (int)floorf(xs0);
    const int col1 = min((int)floorf(xs1) + 1, W - 1);
    const int prows = row1 - row0 + 1;
    const int pcols = col1 - col0 + 1;
    const int psize = prows * pcols;

    // ---- per-lane bin descriptors (patch-relative, channel-invariant) ----
    const int bin = tid & 63;            // wave-local; lanes >=49 idle in compute
    const bool active = bin < PHW;
    int   offs[16];
    float wts[16];
    {
        const int bb = active ? bin : 0;
        const int ph = bb / 7;
        const int pw = bb - ph * 7;
#pragma unroll
        for (int g = 0; g < 4; ++g) {
            const int iy = g >> 1, ix = g & 1;
            const float gy = (float)ph + ((float)iy + 0.5f) * 0.5f;
            const float gx = (float)pw + ((float)ix + 0.5f) * 0.5f;
            const float y = y1 + gy * bin_h;
            const float x = x1 + gx * bin_w;
            const bool valid = (y >= -1.0f) && (y <= (float)H) &&
                               (x >= -1.0f) && (x <= (float)W);
            const float yc = fminf(fmaxf(y, 0.0f), (float)(H - 1));
            const float xc = fminf(fmaxf(x, 0.0f), (float)(W - 1));
            const int yl = (int)floorf(yc);
            const int xl = (int)floorf(xc);
            const int yh = min(yl + 1, H - 1);   // provably in [row0,row1]
            const int xh = min(xl + 1, W - 1);   // provably in [col0,col1]
            const float ly = yc - (float)yl;
            const float lx = xc - (float)xl;
            const float hy = 1.0f - ly, hx = 1.0f - lx;
            const float m = valid ? 0.25f : 0.0f;
            const int ry0 = (yl - row0) * pcols, ry1 = (yh - row0) * pcols;
            const int cx0 = xl - col0, cx1 = xh - col0;
            offs[g * 4 + 0] = ry0 + cx0;  wts[g * 4 + 0] = hy * hx * m;
            offs[g * 4 + 1] = ry0 + cx1;  wts[g * 4 + 1] = hy * lx * m;
            offs[g * 4 + 2] = ry1 + cx0;  wts[g * 4 + 2] = ly * hx * m;
            offs[g * 4 + 3] = ry1 + cx1;  wts[g * 4 + 3] = ly * lx * m;
        }
    }

    __shared__ float lds[NC * PSIZE];
    const int cslot = tid >> 6;          // wave id 0..3 -> channel slot
    const int cbase = chunk * CH;
    const float* __restrict__ fch = feat + (size_t)(b * C + cbase) * HW;
    const int planeOff = row0 * W + col0;
    const size_t outBase = (size_t)r * C * PHW + (size_t)cbase * PHW;

    for (int cc = 0; cc < CH; cc += NC) {
        // ---- coalesced patch load: NC channels, row-major ----
        const int total = NC * psize;
        for (int idx = tid; idx < total; idx += 256) {
            const int ch = idx / psize;
            const int e  = idx - ch * psize;
            const int rr = e / pcols;
            const int cl = e - rr * pcols;
            lds[ch * PSIZE + e] =
                fch[(size_t)(cc + ch) * HW + planeOff + rr * W + cl];
        }
        __syncthreads();

        // ---- bilinear from LDS: wave w handles channel cc+w ----
        if (active) {
            const float* __restrict__ p = &lds[cslot * PSIZE];
            float acc = 0.0f;
#pragma unroll
            for (int k = 0; k < 16; ++k)
                acc += wts[k] * p[offs[k]];
            out[outBase + (size_t)(cc + cslot) * PHW + bin] = acc;
        }
        __syncthreads();
    }
}

extern "C" void kernel_launch(void* const* d_in, const int* in_sizes, int n_in,
                              void* d_out, int out_size, void* d_ws, size_t ws_size,
                              hipStream_t stream) {
    const float* f0 = (const float*)d_in[0];
    const float* f1 = (const float*)d_in[1];
    const float* f2 = (const float*)d_in[2];
    const float* f3 = (const float*)d_in[3];
    const float* boxes = (const float*)d_in[4];
    float* out = (float*)d_out;

    const int R = in_sizes[4] / 4;   // 512 rois
    dim3 grid(R, NCHUNK);
    msroi_kernel<<<grid, 256, 0, stream>>>(f0, f1, f2, f3, boxes, out);
}